// Round 6
// baseline (5914.546 us; speedup 1.0000x reference)
//
#include <hip/hip_runtime.h>
#include <hip/hip_bf16.h>
#include <math.h>

namespace {
constexpr int V = 32000, D = 1024, L = 8, H = 16, T = 128, F = 2816, DH = 64;
constexpr float EPS = 1e-5f;
constexpr float SCALE = 0.125f; // 1/sqrt(DH)
constexpr int QKVN = 3 * D;     // 3072
constexpr int GUN  = 2 * F;     // 5632
constexpr int NP_Q = 8;         // QKV split-K chunks (CH=128)
constexpr int NP_O = 8;         // O-proj chunks
constexpr int NP_G = 8;         // GU chunks
constexpr int NP_D = 22;        // Wd chunks (K=2816 = 22*128)
constexpr int NBLK = 256;       // grid size: <= #CUs -> all blocks co-resident
constexpr int UQ = (QKVN / 64) * NP_Q;  // 384 gemm units
constexpr int UO = (D / 64) * NP_O;     // 128
constexpr int UG = (GUN / 64) * NP_G;   // 704
constexpr int UD = (D / 64) * NP_D;     // 352
}

typedef __attribute__((ext_vector_type(8))) short short8;
typedef __attribute__((ext_vector_type(4))) float f32x4;

__device__ __forceinline__ unsigned short f2bf(float x) {
    union { float f; unsigned u; } v; v.f = x;
    unsigned r = v.u + 0x7FFFu + ((v.u >> 16) & 1u);
    return (unsigned short)(r >> 16);
}

// ---------------- device-scope grid barrier (sense-reversing, gen-counted) ----------------
__device__ __forceinline__ void gridbar(unsigned* bar) {
    __threadfence();   // release: make this block's global writes visible device-wide
    __syncthreads();
    if (threadIdx.x == 0) {
        unsigned gen = __hip_atomic_load(bar + 1, __ATOMIC_RELAXED, __HIP_MEMORY_SCOPE_AGENT);
        unsigned a = __hip_atomic_fetch_add(bar, 1u, __ATOMIC_ACQ_REL, __HIP_MEMORY_SCOPE_AGENT);
        if (a == NBLK - 1) {
            __hip_atomic_store(bar, 0u, __ATOMIC_RELAXED, __HIP_MEMORY_SCOPE_AGENT);
            __hip_atomic_store(bar + 1, gen + 1u, __ATOMIC_RELEASE, __HIP_MEMORY_SCOPE_AGENT);
        } else {
            unsigned g;
            do {
                __builtin_amdgcn_s_sleep(1);
                g = __hip_atomic_load(bar + 1, __ATOMIC_ACQUIRE, __HIP_MEMORY_SCOPE_AGENT);
            } while (g == gen);
        }
    }
    __syncthreads();
    __threadfence();   // acquire: invalidate stale cached lines before next phase reads
}

// ---------------- Embedding gather + RoPE tables (fused) ----------------
__global__ void embed_rope_kernel(const int* __restrict__ ids, const float* __restrict__ emb,
                                  float* __restrict__ X,
                                  float* __restrict__ cosT, float* __restrict__ sinT) {
    int t = blockIdx.x, tid = threadIdx.x;
    int id = ids[t];
    ((float4*)(X + (size_t)t * D))[tid] = ((const float4*)(emb + (size_t)id * D))[tid];
    if (tid < 32) {
        float inv = powf(10000.0f, -(2.0f * (float)tid) / (float)DH);
        float ang = (float)t * inv;
        cosT[t * 32 + tid] = cosf(ang);
        sinT[t * 32 + tid] = sinf(ang);
    }
}

// ---------------- phase helpers (device) ----------------

// rmsnorm over row t: X += sum partials, Y = norm(X)*w (bf16)
__device__ __forceinline__ void rmsnorm_unit(int t, float* __restrict__ X,
                                             const float* __restrict__ P, int np,
                                             const float* __restrict__ w,
                                             unsigned short* __restrict__ Y, float* red) {
    int tid = threadIdx.x;
    float4 xv = ((float4*)(X + (size_t)t * D))[tid];
    for (int c = 0; c < np; ++c) {
        float4 pv = ((const float4*)(P + ((size_t)c * T + t) * D))[tid];
        xv.x += pv.x; xv.y += pv.y; xv.z += pv.z; xv.w += pv.w;
    }
    if (np) ((float4*)(X + (size_t)t * D))[tid] = xv;
    float s = xv.x * xv.x + xv.y * xv.y + xv.z * xv.z + xv.w * xv.w;
    for (int o = 32; o >= 1; o >>= 1) s += __shfl_xor(s, o);
    if ((tid & 63) == 0) red[tid >> 6] = s;
    __syncthreads();
    float tot = red[0] + red[1] + red[2] + red[3];
    float r = rsqrtf(tot / (float)D + EPS);
    float4 wv = ((const float4*)w)[tid];
    ushort4 y;
    y.x = f2bf(xv.x * r * wv.x); y.y = f2bf(xv.y * r * wv.y);
    y.z = f2bf(xv.z * r * wv.z); y.w = f2bf(xv.w * r * wv.w);
    ((ushort4*)(Y + (size_t)t * D))[tid] = y;
}

// one 64-col x 128-k GEMM tile: outP[0..127][outcol0..+63] = A @ W-chunk (plain store)
__device__ __forceinline__ void gemm_unit(const unsigned short* __restrict__ A, int lda,
                                          const float* __restrict__ W, int ldw,
                                          int n0, int k0,
                                          float* __restrict__ outP, int ldo, int outcol0,
                                          unsigned short* Bst) {
    const int tid = threadIdx.x;
    const int wave = tid >> 6, lane = tid & 63;
    const int sc = tid & 63, so = tid >> 6;
    const int lrow = lane & 15, lqo = lane >> 4;
    const float* wCol = W + (size_t)k0 * ldw + n0 + sc;
    float pre[32];
    #pragma unroll
    for (int p = 0; p < 4; ++p) {
        const float* src = wCol + (size_t)((so * 4 + p) * 8) * ldw;
        #pragma unroll
        for (int j = 0; j < 8; ++j) pre[p * 8 + j] = src[(size_t)j * ldw];
    }
    __syncthreads();  // all waves done reading Bst (previous unit/phase)
    unsigned short* wp = Bst + sc * 136;
    #pragma unroll
    for (int p = 0; p < 4; ++p) {
        short8 bv;
        #pragma unroll
        for (int j = 0; j < 8; ++j) bv[j] = (short)f2bf(pre[p * 8 + j]);
        *(short8*)(wp + (so * 4 + p) * 8) = bv;
    }
    __syncthreads();
    f32x4 acc[8] = {};
    const unsigned short* aB = A + (size_t)lrow * lda + k0 + lqo * 8;
    const unsigned short* bRd = Bst + (wave * 16 + lrow) * 136 + lqo * 8;
    #pragma unroll
    for (int ks = 0; ks < 4; ++ks) {
        short8 b = *(const short8*)(bRd + ks * 32);
        #pragma unroll
        for (int mf = 0; mf < 8; ++mf) {
            short8 a = *(const short8*)(aB + (size_t)(mf * 16) * lda + ks * 32);
            acc[mf] = __builtin_amdgcn_mfma_f32_16x16x32_bf16(a, b, acc[mf], 0, 0, 0);
        }
    }
    const int col = outcol0 + wave * 16 + lrow;
    #pragma unroll
    for (int mf = 0; mf < 8; ++mf) {
        int r0 = mf * 16 + lqo * 4;
        #pragma unroll
        for (int r = 0; r < 4; ++r)
            outP[(size_t)(r0 + r) * ldo + col] = acc[mf][r];
    }
}

// QKV partial reduce + RoPE for row t -> compact Q,K,V [T][D]
__device__ __forceinline__ void rope_unit(int t, const float* __restrict__ P,
                                          const float* __restrict__ cosT,
                                          const float* __restrict__ sinT,
                                          float* __restrict__ Qr, float* __restrict__ Kr,
                                          float* __restrict__ Vr) {
    int tid = threadIdx.x;
    int d0 = tid * 4;
    float4 q = {0.f, 0.f, 0.f, 0.f}, k = q, v = q;
    #pragma unroll
    for (int c = 0; c < NP_Q; ++c) {
        const float* base = P + ((size_t)c * T + t) * QKVN;
        float4 a = ((const float4*)base)[tid];
        float4 b = ((const float4*)(base + D))[tid];
        float4 w = ((const float4*)(base + 2 * D))[tid];
        q.x += a.x; q.y += a.y; q.z += a.z; q.w += a.w;
        k.x += b.x; k.y += b.y; k.z += b.z; k.w += b.w;
        v.x += w.x; v.y += w.y; v.z += w.z; v.w += w.w;
    }
    float4 c4 = *(const float4*)(cosT + t * 32 + (d0 & 31));
    float4 s4 = *(const float4*)(sinT + t * 32 + (d0 & 31));
    float sgn = (d0 & 32) ? 1.f : -1.f;
    float4 qp, kp;
    qp.x = __shfl_xor(q.x, 8); qp.y = __shfl_xor(q.y, 8);
    qp.z = __shfl_xor(q.z, 8); qp.w = __shfl_xor(q.w, 8);
    kp.x = __shfl_xor(k.x, 8); kp.y = __shfl_xor(k.y, 8);
    kp.z = __shfl_xor(k.z, 8); kp.w = __shfl_xor(k.w, 8);
    float4 qo, ko;
    qo.x = q.x * c4.x + sgn * qp.x * s4.x; qo.y = q.y * c4.y + sgn * qp.y * s4.y;
    qo.z = q.z * c4.z + sgn * qp.z * s4.z; qo.w = q.w * c4.w + sgn * qp.w * s4.w;
    ko.x = k.x * c4.x + sgn * kp.x * s4.x; ko.y = k.y * c4.y + sgn * kp.y * s4.y;
    ko.z = k.z * c4.z + sgn * kp.z * s4.z; ko.w = k.w * c4.w + sgn * kp.w * s4.w;
    ((float4*)(Qr + (size_t)t * D))[tid] = qo;
    ((float4*)(Kr + (size_t)t * D))[tid] = ko;
    ((float4*)(Vr + (size_t)t * D))[tid] = v;
}

// one (t,h) attention unit, wave-local (no block barrier)
__device__ __forceinline__ void attn_unit(int t, int h, int lane,
                                          const float* __restrict__ Qr,
                                          const float* __restrict__ Kr,
                                          const float* __restrict__ Vr,
                                          unsigned short* __restrict__ AO,
                                          float* qs, float* ps) {
    qs[lane] = Qr[(size_t)t * D + h * DH + lane];
    int j0 = lane, j1 = lane + 64;
    float s0 = -1e30f, s1 = -1e30f;
    if (j0 <= t) {
        const float* kr = Kr + (size_t)j0 * D + h * DH;
        float s = 0.f;
        #pragma unroll
        for (int d = 0; d < DH; ++d) s += qs[d] * kr[d];
        s0 = s * SCALE;
    }
    if (j1 <= t) {
        const float* kr = Kr + (size_t)j1 * D + h * DH;
        float s = 0.f;
        #pragma unroll
        for (int d = 0; d < DH; ++d) s += qs[d] * kr[d];
        s1 = s * SCALE;
    }
    float m = fmaxf(s0, s1);
    for (int o = 32; o >= 1; o >>= 1) m = fmaxf(m, __shfl_xor(m, o));
    float e0 = (j0 <= t) ? __expf(s0 - m) : 0.f;
    float e1 = (j1 <= t) ? __expf(s1 - m) : 0.f;
    float sum = e0 + e1;
    for (int o = 32; o >= 1; o >>= 1) sum += __shfl_xor(sum, o);
    float inv = 1.f / sum;
    ps[j0] = e0 * inv;
    ps[j1] = e1 * inv;
    float acc = 0.f;
    const float* vcol = Vr + h * DH + lane;
    for (int j = 0; j <= t; ++j) acc += ps[j] * vcol[(size_t)j * D];
    AO[(size_t)t * D + h * DH + lane] = f2bf(acc);
}

// silu over row t: Gact[t][f] = silu(sum g)*sum u
__device__ __forceinline__ void silu_unit(int t, const float* __restrict__ P3,
                                          unsigned short* __restrict__ Gact) {
    int tid = threadIdx.x;
    for (int it = 0; it < F / 256; ++it) {
        int f = it * 256 + tid;
        float g = 0.f, u = 0.f;
        #pragma unroll
        for (int c = 0; c < NP_G; ++c) {
            const float* base = P3 + ((size_t)c * T + t) * GUN;
            g += base[f];
            u += base[F + f];
        }
        Gact[(size_t)t * F + f] = f2bf(g / (1.f + __expf(-g)) * u);
    }
}

// ---------------- the per-layer persistent megakernel ----------------
__global__ __launch_bounds__(256)
void layer_kernel(const float* __restrict__ wq, const float* __restrict__ wk,
                  const float* __restrict__ wv, const float* __restrict__ wo,
                  const float* __restrict__ wg, const float* __restrict__ wu,
                  const float* __restrict__ wd,
                  const float* __restrict__ anorm, const float* __restrict__ fnorm,
                  float* __restrict__ X,
                  float* __restrict__ P0, float* __restrict__ P1,
                  float* __restrict__ P2, float* __restrict__ P3,
                  float* __restrict__ Qr, float* __restrict__ Kr, float* __restrict__ Vr,
                  const float* __restrict__ cosT, const float* __restrict__ sinT,
                  unsigned short* __restrict__ Hn, unsigned short* __restrict__ AO,
                  unsigned short* __restrict__ Gact,
                  unsigned* bar, int np_prev) {
    __shared__ unsigned short Bst[64 * 136];
    __shared__ float red[4];
    __shared__ float attnQ[4 * 64];
    __shared__ float attnP[4 * 128];
    const int blk = blockIdx.x;

    // A: X += prev Wd partials; Hn = rmsnorm(X)*anorm
    if (blk < T) rmsnorm_unit(blk, X, P2, np_prev, anorm, Hn, red);
    gridbar(bar);
    // B: QKV GEMM -> P0 partials
    for (int u = blk; u < UQ; u += NBLK) {
        int ct = u % (QKVN / 64), kc = u / (QKVN / 64);
        int n0g = ct * 64, z = n0g >> 10;
        const float* W = z == 0 ? wq : (z == 1 ? wk : wv);
        gemm_unit(Hn, D, W, D, n0g & 1023, kc * 128,
                  P0 + (size_t)kc * T * QKVN, QKVN, n0g, Bst);
    }
    gridbar(bar);
    // C: reduce + RoPE -> Qr,Kr,Vr
    if (blk < T) rope_unit(blk, P0, cosT, sinT, Qr, Kr, Vr);
    gridbar(bar);
    // D: attention (2048 wave-units, balanced: fixed h per block, t spread)
    {
        int wave = threadIdx.x >> 6, lane = threadIdx.x & 63;
        #pragma unroll
        for (int i = 0; i < 2; ++i) {
            int uu = blk + (wave * 2 + i) * NBLK;
            attn_unit(uu >> 4, uu & 15, lane, Qr, Kr, Vr, AO,
                      attnQ + wave * 64, attnP + wave * 128);
        }
    }
    gridbar(bar);
    // E: O-proj -> P1 partials
    for (int u = blk; u < UO; u += NBLK) {
        int ct = u % 16, kc = u / 16;
        gemm_unit(AO, D, wo, D, ct * 64, kc * 128,
                  P1 + (size_t)kc * T * D, D, ct * 64, Bst);
    }
    gridbar(bar);
    // F: X += P1; Hn = rmsnorm(X)*fnorm
    if (blk < T) rmsnorm_unit(blk, X, P1, NP_O, fnorm, Hn, red);
    gridbar(bar);
    // G: GU GEMM -> P3 partials
    for (int u = blk; u < UG; u += NBLK) {
        int ct = u % (GUN / 64), kc = u / (GUN / 64);
        int n0g = ct * 64;
        const float* W = n0g < F ? wg : wu;
        int n0 = n0g < F ? n0g : n0g - F;
        gemm_unit(Hn, D, W, F, n0, kc * 128,
                  P3 + (size_t)kc * T * GUN, GUN, n0g, Bst);
    }
    gridbar(bar);
    // H: silu reduce -> Gact
    if (blk < T) silu_unit(blk, P3, Gact);
    gridbar(bar);
    // I: Wd -> P2 partials (consumed by next layer's phase A / final norm)
    for (int u = blk; u < UD; u += NBLK) {
        int ct = u % 16, kc = u / 16;
        gemm_unit(Gact, F, wd, D, ct * 64, kc * 128,
                  P2 + (size_t)kc * T * D, D, ct * 64, Bst);
    }
}

// ---------------- final norm of last token (adds last Wd partials) ----------------
__global__ void final_norm_kernel(float* __restrict__ X, const float* __restrict__ P2,
                                  const float* __restrict__ w, float* __restrict__ xl) {
    int tid = threadIdx.x;
    float4 xv = ((float4*)(X + (size_t)(T - 1) * D))[tid];
    #pragma unroll
    for (int c = 0; c < NP_D; ++c) {
        float4 pv = ((const float4*)(P2 + ((size_t)c * T + (T - 1)) * D))[tid];
        xv.x += pv.x; xv.y += pv.y; xv.z += pv.z; xv.w += pv.w;
    }
    float s = xv.x * xv.x + xv.y * xv.y + xv.z * xv.z + xv.w * xv.w;
    for (int o = 32; o >= 1; o >>= 1) s += __shfl_xor(s, o);
    __shared__ float red[4];
    if ((tid & 63) == 0) red[tid >> 6] = s;
    __syncthreads();
    float tot = red[0] + red[1] + red[2] + red[3];
    float r = rsqrtf(tot / (float)D + EPS);
    float4 wv = ((const float4*)w)[tid];
    float4 y;
    y.x = xv.x * r * wv.x; y.y = xv.y * r * wv.y;
    y.z = xv.z * r * wv.z; y.w = xv.w * r * wv.w;
    ((float4*)(xl))[tid] = y;
}

// ---------------- logits: out[v] = emb[v,:] . xl ----------------
__global__ void logits_kernel(const float* __restrict__ emb, const float* __restrict__ xl,
                              float* __restrict__ out) {
    __shared__ float x[D];
    int tid = threadIdx.x;
    ((float4*)x)[tid] = ((const float4*)xl)[tid];
    __syncthreads();
    int row = blockIdx.x * 4 + (tid >> 6);
    int lane = tid & 63;
    const float4* e4 = (const float4*)(emb + (size_t)row * D);
    const float4* x4 = (const float4*)x;
    float s = 0.f;
    #pragma unroll
    for (int k = lane; k < D / 4; k += 64) {
        float4 ev = e4[k], xv = x4[k];
        s += ev.x * xv.x + ev.y * xv.y + ev.z * xv.z + ev.w * xv.w;
    }
    for (int o = 32; o >= 1; o >>= 1) s += __shfl_xor(s, o);
    if (lane == 0) out[row] = s;
}

extern "C" void kernel_launch(void* const* d_in, const int* in_sizes, int n_in,
                              void* d_out, int out_size, void* d_ws, size_t ws_size,
                              hipStream_t stream) {
    const int*   ids = (const int*)d_in[0];
    const float* emb = (const float*)d_in[1];
    const float* Wq  = (const float*)d_in[2];
    const float* Wk  = (const float*)d_in[3];
    const float* Wv  = (const float*)d_in[4];
    const float* Wo  = (const float*)d_in[5];
    const float* Wg  = (const float*)d_in[6];
    const float* Wu  = (const float*)d_in[7];
    const float* Wd  = (const float*)d_in[8];
    const float* attn_norm = (const float*)d_in[9];
    const float* ffn_norm  = (const float*)d_in[10];
    const float* norm_out  = (const float*)d_in[11];
    float* out = (float*)d_out;

    size_t off = 0;
    auto alloc = [&](size_t bytes) {
        void* p = (char*)d_ws + off;
        off += (bytes + 255) & ~(size_t)255;
        return p;
    };
    unsigned*       bar   = (unsigned*)alloc(64);
    float*          X     = (float*)alloc((size_t)T * D * 4);
    float*          P0    = (float*)alloc((size_t)NP_Q * T * QKVN * 4);
    float*          P1    = (float*)alloc((size_t)NP_O * T * D * 4);
    float*          P2    = (float*)alloc((size_t)NP_D * T * D * 4);
    float*          P3    = (float*)alloc((size_t)NP_G * T * GUN * 4);
    float*          Qr    = (float*)alloc((size_t)T * D * 4);
    float*          Kr    = (float*)alloc((size_t)T * D * 4);
    float*          Vr    = (float*)alloc((size_t)T * D * 4);
    float*          cosT  = (float*)alloc((size_t)T * 32 * 4);
    float*          sinT  = (float*)alloc((size_t)T * 32 * 4);
    float*          xl    = (float*)alloc((size_t)D * 4);
    unsigned short* Hn_bf = (unsigned short*)alloc((size_t)T * D * 2);
    unsigned short* AO_bf = (unsigned short*)alloc((size_t)T * D * 2);
    unsigned short* Gact  = (unsigned short*)alloc((size_t)T * F * 2);
    (void)ws_size;

    hipMemsetAsync(bar, 0, 64, stream);  // barrier state: deterministic per call
    embed_rope_kernel<<<T, 256, 0, stream>>>(ids, emb, X, cosT, sinT);

    for (int l = 0; l < L; ++l) {
        layer_kernel<<<NBLK, 256, 0, stream>>>(
            Wq + (size_t)l * D * D, Wk + (size_t)l * D * D,
            Wv + (size_t)l * D * D, Wo + (size_t)l * D * D,
            Wg + (size_t)l * D * F, Wu + (size_t)l * D * F,
            Wd + (size_t)l * F * D,
            attn_norm + (size_t)l * D, ffn_norm + (size_t)l * D,
            X, P0, P1, P2, P3, Qr, Kr, Vr, cosT, sinT,
            Hn_bf, AO_bf, Gact, bar, l == 0 ? 0 : NP_D);
    }

    final_norm_kernel<<<1, 256, 0, stream>>>(X, P2, norm_out, xl);
    logits_kernel<<<V / 4, 256, 0, stream>>>(emb, xl, out);
}

// Round 7
// 2749.949 us; speedup vs baseline: 2.1508x; 2.1508x over previous
//
#include <hip/hip_runtime.h>
#include <hip/hip_bf16.h>
#include <math.h>

namespace {
constexpr int V = 32000, D = 1024, L = 8, H = 16, T = 128, F = 2816, DH = 64;
constexpr float EPS = 1e-5f;
constexpr float SCALE = 0.125f; // 1/sqrt(DH)
constexpr int QKVN = 3 * D;     // 3072
constexpr int GUN  = 2 * F;     // 5632
constexpr int NP_Q = 8;         // QKV split-K chunks (CH=128)
constexpr int NP_O = 8;         // O-proj chunks
constexpr int NP_G = 8;         // GU chunks
constexpr int NP_D = 22;        // Wd chunks (K=2816 = 22*128)
constexpr int NBLK = 1024;      // 4 blocks/CU, co-resident via __launch_bounds__(256,4)
constexpr int NW   = NBLK * 4;  // 4096 waves
constexpr int NSUB = 16;
constexpr int QUOTA = NBLK / NSUB;        // 64 arrivals per sub-counter
constexpr int SLOT_STRIDE = 544;          // uints per barrier instance (16 subs*32 + master)
constexpr int UQ = (QKVN / 16) * NP_Q;    // 1536 wave units
constexpr int UO = (D / 16) * NP_O;       // 512
constexpr int UG = (GUN / 16) * NP_G;     // 2816
constexpr int UD = (D / 16) * NP_D;       // 1408
}

typedef __attribute__((ext_vector_type(8))) short short8;
typedef __attribute__((ext_vector_type(4))) float f32x4;

__device__ __forceinline__ unsigned short f2bf(float x) {
    union { float f; unsigned u; } v; v.f = x;
    unsigned r = v.u + 0x7FFFu + ((v.u >> 16) & 1u);
    return (unsigned short)(r >> 16);
}

// ---- grid barrier: 2-level arrive, RELAXED spin, one acquire at exit ----
// slot layout: sub[i] at +i*32, master at +512. Each slot used ONCE per call.
__device__ __forceinline__ void gridbar(unsigned* slot) {
    __syncthreads();
    if (threadIdx.x == 0) {
        unsigned* subp = slot + (blockIdx.x & (NSUB - 1)) * 32;
        unsigned* mast = slot + 512;
        // release-arrive: writes back this block's stores (wbl2) before counting in
        unsigned prev = __hip_atomic_fetch_add(subp, 1u, __ATOMIC_RELEASE,
                                               __HIP_MEMORY_SCOPE_AGENT);
        if (prev == QUOTA - 1)
            __hip_atomic_fetch_add(mast, 1u, __ATOMIC_RELEASE, __HIP_MEMORY_SCOPE_AGENT);
        // relaxed spin: no per-poll cache invalidate
        while (__hip_atomic_load(mast, __ATOMIC_RELAXED, __HIP_MEMORY_SCOPE_AGENT)
               != (unsigned)NSUB)
            __builtin_amdgcn_s_sleep(2);
        // single acquire: invalidate stale L1/L2 once before next phase reads
        (void)__hip_atomic_load(mast, __ATOMIC_ACQUIRE, __HIP_MEMORY_SCOPE_AGENT);
    }
    __syncthreads();
}

// ---------------- Embedding gather + RoPE tables (fused) ----------------
__global__ void embed_rope_kernel(const int* __restrict__ ids, const float* __restrict__ emb,
                                  float* __restrict__ X,
                                  float* __restrict__ cosT, float* __restrict__ sinT) {
    int t = blockIdx.x, tid = threadIdx.x;
    int id = ids[t];
    ((float4*)(X + (size_t)t * D))[tid] = ((const float4*)(emb + (size_t)id * D))[tid];
    if (tid < 32) {
        float inv = powf(10000.0f, -(2.0f * (float)tid) / (float)DH);
        float ang = (float)t * inv;
        cosT[t * 32 + tid] = cosf(ang);
        sinT[t * 32 + tid] = sinf(ang);
    }
}

// ---------------- wave-level phase units ----------------

// rmsnorm row t (one wave): X[t,:] += sum partials; Y = norm(X)*w (bf16)
__device__ __forceinline__ void rmsnorm_unit(int t, int lane, float* __restrict__ X,
                                             const float* __restrict__ P, int np,
                                             const float* __restrict__ w,
                                             unsigned short* __restrict__ Y) {
    const int base = t * D + lane * 16;
    float4 xv[4];
    #pragma unroll
    for (int q = 0; q < 4; ++q) xv[q] = *(const float4*)(X + base + q * 4);
    for (int c = 0; c < np; ++c) {
        const float* pb = P + (size_t)c * T * D + base;
        #pragma unroll
        for (int q = 0; q < 4; ++q) {
            float4 pv = *(const float4*)(pb + q * 4);
            xv[q].x += pv.x; xv[q].y += pv.y; xv[q].z += pv.z; xv[q].w += pv.w;
        }
    }
    if (np) {
        #pragma unroll
        for (int q = 0; q < 4; ++q) *(float4*)(X + base + q * 4) = xv[q];
    }
    float s = 0.f;
    #pragma unroll
    for (int q = 0; q < 4; ++q)
        s += xv[q].x * xv[q].x + xv[q].y * xv[q].y + xv[q].z * xv[q].z + xv[q].w * xv[q].w;
    for (int o = 32; o >= 1; o >>= 1) s += __shfl_xor(s, o);
    float r = rsqrtf(s / (float)D + EPS);
    #pragma unroll
    for (int q = 0; q < 4; ++q) {
        float4 wv = *(const float4*)(w + lane * 16 + q * 4);
        ushort4 y;
        y.x = f2bf(xv[q].x * r * wv.x); y.y = f2bf(xv[q].y * r * wv.y);
        y.z = f2bf(xv[q].z * r * wv.z); y.w = f2bf(xv[q].w * r * wv.w);
        *(ushort4*)(Y + base + q * 4) = y;
    }
}

// one 16-col x 128-k GEMM tile per wave; B loaded fp32 direct (no LDS), converted in-reg
__device__ __forceinline__ void gemm_unit(int lane, const unsigned short* __restrict__ A,
                                          int lda, const float* __restrict__ W, int ldw,
                                          int n0, int k0,
                                          float* __restrict__ outP, int ldo, int outcol0) {
    const int lrow = lane & 15, lqo = lane >> 4;
    const unsigned short* aB = A + (size_t)lrow * lda + k0 + lqo * 8;
    const float* wB = W + (size_t)k0 * ldw + n0 + lrow;
    f32x4 acc[8] = {};
    #pragma unroll
    for (int ks = 0; ks < 4; ++ks) {
        const float* wk = wB + (size_t)(ks * 32 + lqo * 8) * ldw;
        float bf[8];
        #pragma unroll
        for (int j = 0; j < 8; ++j) bf[j] = wk[(size_t)j * ldw];
        short8 b;
        #pragma unroll
        for (int j = 0; j < 8; ++j) b[j] = (short)f2bf(bf[j]);
        #pragma unroll
        for (int mf = 0; mf < 8; ++mf) {
            short8 a = *(const short8*)(aB + (size_t)(mf * 16) * lda + ks * 32);
            acc[mf] = __builtin_amdgcn_mfma_f32_16x16x32_bf16(a, b, acc[mf], 0, 0, 0);
        }
    }
    const int col = outcol0 + lrow;
    #pragma unroll
    for (int mf = 0; mf < 8; ++mf) {
        int r0 = mf * 16 + lqo * 4;
        #pragma unroll
        for (int r = 0; r < 4; ++r)
            outP[(size_t)(r0 + r) * ldo + col] = acc[mf][r];
    }
}

// QKV partial reduce + RoPE: one wave handles row t, 256-dim quarter qn (4 heads)
__device__ __forceinline__ void rope_unit(int t, int qn, int lane,
                                          const float* __restrict__ P,
                                          const float* __restrict__ cosT,
                                          const float* __restrict__ sinT,
                                          float* __restrict__ Qr, float* __restrict__ Kr,
                                          float* __restrict__ Vr) {
    const int d0 = qn * 256 + lane * 4;
    float4 q = {0.f, 0.f, 0.f, 0.f}, k = q, v = q;
    #pragma unroll
    for (int c = 0; c < NP_Q; ++c) {
        const float* base = P + ((size_t)c * T + t) * QKVN;
        float4 a = *(const float4*)(base + d0);
        float4 b = *(const float4*)(base + D + d0);
        float4 w = *(const float4*)(base + 2 * D + d0);
        q.x += a.x; q.y += a.y; q.z += a.z; q.w += a.w;
        k.x += b.x; k.y += b.y; k.z += b.z; k.w += b.w;
        v.x += w.x; v.y += w.y; v.z += w.z; v.w += w.w;
    }
    float4 c4 = *(const float4*)(cosT + t * 32 + (d0 & 31));
    float4 s4 = *(const float4*)(sinT + t * 32 + (d0 & 31));
    float sgn = (d0 & 32) ? 1.f : -1.f;
    float4 qp, kp;
    qp.x = __shfl_xor(q.x, 8); qp.y = __shfl_xor(q.y, 8);
    qp.z = __shfl_xor(q.z, 8); qp.w = __shfl_xor(q.w, 8);
    kp.x = __shfl_xor(k.x, 8); kp.y = __shfl_xor(k.y, 8);
    kp.z = __shfl_xor(k.z, 8); kp.w = __shfl_xor(k.w, 8);
    float4 qo, ko;
    qo.x = q.x * c4.x + sgn * qp.x * s4.x; qo.y = q.y * c4.y + sgn * qp.y * s4.y;
    qo.z = q.z * c4.z + sgn * qp.z * s4.z; qo.w = q.w * c4.w + sgn * qp.w * s4.w;
    ko.x = k.x * c4.x + sgn * kp.x * s4.x; ko.y = k.y * c4.y + sgn * kp.y * s4.y;
    ko.z = k.z * c4.z + sgn * kp.z * s4.z; ko.w = k.w * c4.w + sgn * kp.w * s4.w;
    *(float4*)(Qr + (size_t)t * D + d0) = qo;
    *(float4*)(Kr + (size_t)t * D + d0) = ko;
    *(float4*)(Vr + (size_t)t * D + d0) = v;
}

// one (t,h) attention unit, wave-local
__device__ __forceinline__ void attn_unit(int t, int h, int lane,
                                          const float* __restrict__ Qr,
                                          const float* __restrict__ Kr,
                                          const float* __restrict__ Vr,
                                          unsigned short* __restrict__ AO,
                                          float* qs, float* ps) {
    qs[lane] = Qr[(size_t)t * D + h * DH + lane];
    int j0 = lane, j1 = lane + 64;
    float s0 = -1e30f, s1 = -1e30f;
    if (j0 <= t) {
        const float* kr = Kr + (size_t)j0 * D + h * DH;
        float s = 0.f;
        #pragma unroll
        for (int d = 0; d < DH; ++d) s += qs[d] * kr[d];
        s0 = s * SCALE;
    }
    if (j1 <= t) {
        const float* kr = Kr + (size_t)j1 * D + h * DH;
        float s = 0.f;
        #pragma unroll
        for (int d = 0; d < DH; ++d) s += qs[d] * kr[d];
        s1 = s * SCALE;
    }
    float m = fmaxf(s0, s1);
    for (int o = 32; o >= 1; o >>= 1) m = fmaxf(m, __shfl_xor(m, o));
    float e0 = (j0 <= t) ? __expf(s0 - m) : 0.f;
    float e1 = (j1 <= t) ? __expf(s1 - m) : 0.f;
    float sum = e0 + e1;
    for (int o = 32; o >= 1; o >>= 1) sum += __shfl_xor(sum, o);
    float inv = 1.f / sum;
    ps[j0] = e0 * inv;
    ps[j1] = e1 * inv;
    float acc = 0.f;
    const float* vcol = Vr + h * DH + lane;
    for (int j = 0; j <= t; ++j) acc += ps[j] * vcol[(size_t)j * D];
    AO[(size_t)t * D + h * DH + lane] = f2bf(acc);
}

// silu reduce: wave handles row t, 256-wide f-chunk fq (lane: 4 f's)
__device__ __forceinline__ void silu_unit(int t, int fq, int lane,
                                          const float* __restrict__ P3,
                                          unsigned short* __restrict__ Gact) {
    const int f0 = fq * 256 + lane * 4;
    float4 g = {0.f, 0.f, 0.f, 0.f}, u = g;
    #pragma unroll
    for (int c = 0; c < NP_G; ++c) {
        const float* base = P3 + ((size_t)c * T + t) * GUN;
        float4 a = *(const float4*)(base + f0);
        float4 b = *(const float4*)(base + F + f0);
        g.x += a.x; g.y += a.y; g.z += a.z; g.w += a.w;
        u.x += b.x; u.y += b.y; u.z += b.z; u.w += b.w;
    }
    ushort4 y;
    y.x = f2bf(g.x / (1.f + __expf(-g.x)) * u.x);
    y.y = f2bf(g.y / (1.f + __expf(-g.y)) * u.y);
    y.z = f2bf(g.z / (1.f + __expf(-g.z)) * u.z);
    y.w = f2bf(g.w / (1.f + __expf(-g.w)) * u.w);
    *(ushort4*)(Gact + (size_t)t * F + f0) = y;
}

// ---------------- per-layer persistent megakernel ----------------
__global__ __launch_bounds__(256, 4)
void layer_kernel(const float* __restrict__ wq, const float* __restrict__ wk,
                  const float* __restrict__ wv, const float* __restrict__ wo,
                  const float* __restrict__ wg, const float* __restrict__ wu,
                  const float* __restrict__ wd,
                  const float* __restrict__ anorm, const float* __restrict__ fnorm,
                  float* __restrict__ X,
                  float* __restrict__ P0, float* __restrict__ P1,
                  float* __restrict__ P2, float* __restrict__ P3,
                  float* __restrict__ Qr, float* __restrict__ Kr, float* __restrict__ Vr,
                  const float* __restrict__ cosT, const float* __restrict__ sinT,
                  unsigned short* __restrict__ Hn, unsigned short* __restrict__ AO,
                  unsigned short* __restrict__ Gact,
                  unsigned* bar, int np_prev) {
    __shared__ float attnQ[4][64];
    __shared__ float attnP[4][128];
    const int wave = threadIdx.x >> 6, lane = threadIdx.x & 63;
    const int gw = blockIdx.x * 4 + wave;   // 0..4095

    // A: X += prev Wd partials; Hn = rmsnorm(X)*anorm
    if (gw < T) rmsnorm_unit(gw, lane, X, P2, np_prev, anorm, Hn);
    gridbar(bar + 0 * SLOT_STRIDE);
    // B: QKV -> P0 partials (1536 units: 192 col-strips x 8 k-chunks)
    if (gw < UQ) {
        int ct = gw % (QKVN / 16), kc = gw / (QKVN / 16);
        int n0g = ct * 16, z = n0g >> 10;
        const float* W = z == 0 ? wq : (z == 1 ? wk : wv);
        gemm_unit(lane, Hn, D, W, D, n0g & 1023, kc * 128,
                  P0 + (size_t)kc * T * QKVN, QKVN, n0g);
    }
    gridbar(bar + 1 * SLOT_STRIDE);
    // C: reduce + RoPE (512 units: t x 4 quarters)
    if (gw < 512) rope_unit(gw >> 2, gw & 3, lane, P0, cosT, sinT, Qr, Kr, Vr);
    gridbar(bar + 2 * SLOT_STRIDE);
    // D: attention (2048 (t,h) wave units)
    if (gw < 2048)
        attn_unit(gw >> 4, gw & 15, lane, Qr, Kr, Vr, AO, attnQ[wave], attnP[wave]);
    gridbar(bar + 3 * SLOT_STRIDE);
    // E: O-proj -> P1 (512 units)
    if (gw < UO) {
        int ct = gw & 63, kc = gw >> 6;
        gemm_unit(lane, AO, D, wo, D, ct * 16, kc * 128,
                  P1 + (size_t)kc * T * D, D, ct * 16);
    }
    gridbar(bar + 4 * SLOT_STRIDE);
    // F: X += P1; Hn = rmsnorm(X)*fnorm
    if (gw < T) rmsnorm_unit(gw, lane, X, P1, NP_O, fnorm, Hn);
    gridbar(bar + 5 * SLOT_STRIDE);
    // G: GU -> P3 (2816 units: 352 col-strips x 8 k-chunks)
    if (gw < UG) {
        int ct = gw % (GUN / 16), kc = gw / (GUN / 16);
        int n0g = ct * 16;
        const float* W = n0g < F ? wg : wu;
        int n0 = n0g < F ? n0g : n0g - F;
        gemm_unit(lane, Hn, D, W, F, n0, kc * 128,
                  P3 + (size_t)kc * T * GUN, GUN, n0g);
    }
    gridbar(bar + 6 * SLOT_STRIDE);
    // H: silu reduce -> Gact (1408 units: t x 11 chunks)
    if (gw < 1408) silu_unit(gw & 127, gw >> 7, lane, P3, Gact);
    gridbar(bar + 7 * SLOT_STRIDE);
    // I: Wd -> P2 (1408 units: 64 col-strips x 22 k-chunks)
    if (gw < UD) {
        int ct = gw & 63, kc = gw >> 6;
        gemm_unit(lane, Gact, F, wd, D, ct * 16, kc * 128,
                  P2 + (size_t)kc * T * D, D, ct * 16);
    }
}

// ---------------- final norm of last token (adds last Wd partials) ----------------
__global__ void final_norm_kernel(float* __restrict__ X, const float* __restrict__ P2,
                                  const float* __restrict__ w, float* __restrict__ xl) {
    int tid = threadIdx.x;
    float4 xv = ((float4*)(X + (size_t)(T - 1) * D))[tid];
    #pragma unroll
    for (int c = 0; c < NP_D; ++c) {
        float4 pv = ((const float4*)(P2 + ((size_t)c * T + (T - 1)) * D))[tid];
        xv.x += pv.x; xv.y += pv.y; xv.z += pv.z; xv.w += pv.w;
    }
    float s = xv.x * xv.x + xv.y * xv.y + xv.z * xv.z + xv.w * xv.w;
    for (int o = 32; o >= 1; o >>= 1) s += __shfl_xor(s, o);
    __shared__ float red[4];
    if ((tid & 63) == 0) red[tid >> 6] = s;
    __syncthreads();
    float tot = red[0] + red[1] + red[2] + red[3];
    float r = rsqrtf(tot / (float)D + EPS);
    float4 wv = ((const float4*)w)[tid];
    float4 y;
    y.x = xv.x * r * wv.x; y.y = xv.y * r * wv.y;
    y.z = xv.z * r * wv.z; y.w = xv.w * r * wv.w;
    ((float4*)(xl))[tid] = y;
}

// ---------------- logits: out[v] = emb[v,:] . xl ----------------
__global__ void logits_kernel(const float* __restrict__ emb, const float* __restrict__ xl,
                              float* __restrict__ out) {
    __shared__ float x[D];
    int tid = threadIdx.x;
    ((float4*)x)[tid] = ((const float4*)xl)[tid];
    __syncthreads();
    int row = blockIdx.x * 4 + (tid >> 6);
    int lane = tid & 63;
    const float4* e4 = (const float4*)(emb + (size_t)row * D);
    const float4* x4 = (const float4*)x;
    float s = 0.f;
    #pragma unroll
    for (int k = lane; k < D / 4; k += 64) {
        float4 ev = e4[k], xv = x4[k];
        s += ev.x * xv.x + ev.y * xv.y + ev.z * xv.z + ev.w * xv.w;
    }
    for (int o = 32; o >= 1; o >>= 1) s += __shfl_xor(s, o);
    if (lane == 0) out[row] = s;
}

extern "C" void kernel_launch(void* const* d_in, const int* in_sizes, int n_in,
                              void* d_out, int out_size, void* d_ws, size_t ws_size,
                              hipStream_t stream) {
    const int*   ids = (const int*)d_in[0];
    const float* emb = (const float*)d_in[1];
    const float* Wq  = (const float*)d_in[2];
    const float* Wk  = (const float*)d_in[3];
    const float* Wv  = (const float*)d_in[4];
    const float* Wo  = (const float*)d_in[5];
    const float* Wg  = (const float*)d_in[6];
    const float* Wu  = (const float*)d_in[7];
    const float* Wd  = (const float*)d_in[8];
    const float* attn_norm = (const float*)d_in[9];
    const float* ffn_norm  = (const float*)d_in[10];
    const float* norm_out  = (const float*)d_in[11];
    float* out = (float*)d_out;

    size_t off = 0;
    auto alloc = [&](size_t bytes) {
        void* p = (char*)d_ws + off;
        off += (bytes + 255) & ~(size_t)255;
        return p;
    };
    unsigned*       bar   = (unsigned*)alloc((size_t)L * 8 * SLOT_STRIDE * 4);
    float*          X     = (float*)alloc((size_t)T * D * 4);
    float*          P0    = (float*)alloc((size_t)NP_Q * T * QKVN * 4);
    float*          P1    = (float*)alloc((size_t)NP_O * T * D * 4);
    float*          P2    = (float*)alloc((size_t)NP_D * T * D * 4);
    float*          P3    = (float*)alloc((size_t)NP_G * T * GUN * 4);
    float*          Qr    = (float*)alloc((size_t)T * D * 4);
    float*          Kr    = (float*)alloc((size_t)T * D * 4);
    float*          Vr    = (float*)alloc((size_t)T * D * 4);
    float*          cosT  = (float*)alloc((size_t)T * 32 * 4);
    float*          sinT  = (float*)alloc((size_t)T * 32 * 4);
    float*          xl    = (float*)alloc((size_t)D * 4);
    unsigned short* Hn_bf = (unsigned short*)alloc((size_t)T * D * 2);
    unsigned short* AO_bf = (unsigned short*)alloc((size_t)T * D * 2);
    unsigned short* Gact  = (unsigned short*)alloc((size_t)T * F * 2);
    (void)ws_size;

    // zero all barrier slots once per call (graph includes this each replay)
    hipMemsetAsync(bar, 0, (size_t)L * 8 * SLOT_STRIDE * 4, stream);
    embed_rope_kernel<<<T, 256, 0, stream>>>(ids, emb, X, cosT, sinT);

    for (int l = 0; l < L; ++l) {
        layer_kernel<<<NBLK, 256, 0, stream>>>(
            Wq + (size_t)l * D * D, Wk + (size_t)l * D * D,
            Wv + (size_t)l * D * D, Wo + (size_t)l * D * D,
            Wg + (size_t)l * D * F, Wu + (size_t)l * D * F,
            Wd + (size_t)l * F * D,
            attn_norm + (size_t)l * D, ffn_norm + (size_t)l * D,
            X, P0, P1, P2, P3, Qr, Kr, Vr, cosT, sinT,
            Hn_bf, AO_bf, Gact,
            bar + (size_t)l * 8 * SLOT_STRIDE, l == 0 ? 0 : NP_D);
    }

    final_norm_kernel<<<1, 256, 0, stream>>>(X, P2, norm_out, xl);
    logits_kernel<<<V / 4, 256, 0, stream>>>(emb, xl, out);
}

// Round 8
// 921.055 us; speedup vs baseline: 6.4215x; 2.9857x over previous
//
#include <hip/hip_runtime.h>
#include <hip/hip_bf16.h>
#include <math.h>

namespace {
constexpr int V = 32000, D = 1024, L = 8, H = 16, T = 128, F = 2816, DH = 64;
constexpr float EPS = 1e-5f;
constexpr float SCALE = 0.125f; // 1/sqrt(DH)
constexpr int QKVN = 3 * D;     // 3072
constexpr int NP_O = 8;         // O-proj split-K chunks (CH=128)
constexpr int NP_D = 11;        // Wd chunks (K=2816 = 11*256)
}

typedef __attribute__((ext_vector_type(8))) short short8;
typedef __attribute__((ext_vector_type(4))) float f32x4;

__device__ __forceinline__ unsigned short f2bf(float x) {
    union { float f; unsigned u; } v; v.f = x;
    unsigned r = v.u + 0x7FFFu + ((v.u >> 16) & 1u);
    return (unsigned short)(r >> 16);
}

// ---------------- Embedding gather + RoPE tables (fused) ----------------
__global__ void embed_rope_kernel(const int* __restrict__ ids, const float* __restrict__ emb,
                                  float* __restrict__ X,
                                  float* __restrict__ cosT, float* __restrict__ sinT) {
    int t = blockIdx.x, tid = threadIdx.x;
    int id = ids[t];
    ((float4*)(X + (size_t)t * D))[tid] = ((const float4*)(emb + (size_t)id * D))[tid];
    if (tid < 32) {
        float inv = powf(10000.0f, -(2.0f * (float)tid) / (float)DH);
        float ang = (float)t * inv;
        cosT[t * 32 + tid] = cosf(ang);
        sinT[t * 32 + tid] = sinf(ang);
    }
}

// ---------------- RMSNorm + unrolled partial-sum residual update ----------------
template<int NP, bool BF16OUT>
__launch_bounds__(256)
__global__ void rmsnorm_sum_kernel(float* __restrict__ X, const float* __restrict__ P,
                                   const float* __restrict__ w, void* __restrict__ Y) {
    int t = blockIdx.x, tid = threadIdx.x;
    float4 xv = ((float4*)(X + (size_t)t * D))[tid];
    #pragma unroll
    for (int c = 0; c < NP; ++c) {
        float4 pv = ((const float4*)(P + ((size_t)c * T + t) * D))[tid];
        xv.x += pv.x; xv.y += pv.y; xv.z += pv.z; xv.w += pv.w;
    }
    if (NP) ((float4*)(X + (size_t)t * D))[tid] = xv;
    float s = xv.x * xv.x + xv.y * xv.y + xv.z * xv.z + xv.w * xv.w;
    for (int o = 32; o >= 1; o >>= 1) s += __shfl_xor(s, o);
    __shared__ float red[4];
    if ((tid & 63) == 0) red[tid >> 6] = s;
    __syncthreads();
    float tot = red[0] + red[1] + red[2] + red[3];
    float r = rsqrtf(tot / (float)D + EPS);
    float4 wv = ((const float4*)w)[tid];
    if (BF16OUT) {
        ushort4 y;
        y.x = f2bf(xv.x * r * wv.x); y.y = f2bf(xv.y * r * wv.y);
        y.z = f2bf(xv.z * r * wv.z); y.w = f2bf(xv.w * r * wv.w);
        ((ushort4*)((unsigned short*)Y + (size_t)t * D))[tid] = y;
    } else {
        float4 y;
        y.x = xv.x * r * wv.x; y.y = xv.y * r * wv.y;
        y.z = xv.z * r * wv.z; y.w = xv.w * r * wv.w;
        ((float4*)((float*)Y + (size_t)t * D))[tid] = y;
    }
}

// ---------------- QKV full-K fused GEMM: QKV[128][3072] = Hn @ {Wq|Wk|Wv} ----------------
// 192 blocks x 16 cols; 4 waves each own a K/4=256 slice (per-lane strided fp32 loads,
// batched 32-deep); cross-wave reduce through LDS; direct fp32 store.
__launch_bounds__(256)
__global__ void gemm_qkv_kernel(const unsigned short* __restrict__ A,
                                const float* __restrict__ Wq, const float* __restrict__ Wk,
                                const float* __restrict__ Wv, float* __restrict__ QKV) {
    __shared__ float Ls[4][128][17];
    const int tid = threadIdx.x, wave = tid >> 6, lane = tid & 63;
    const int lrow = lane & 15, lqo = lane >> 4;
    const int n16 = blockIdx.x * 16;
    const int z = n16 >> 10;
    const float* W = z == 0 ? Wq : (z == 1 ? Wk : Wv);
    const int n0 = n16 & 1023;
    const int k0 = wave * 256;
    const unsigned short* aB = A + (size_t)lrow * D + k0 + lqo * 8;
    const float* wB = W + (size_t)(k0 + lqo * 8) * D + n0 + lrow;
    f32x4 acc[8] = {};
    #pragma unroll
    for (int half = 0; half < 2; ++half) {
        float pre[32];
        #pragma unroll
        for (int ks = 0; ks < 4; ++ks)
            #pragma unroll
            for (int j = 0; j < 8; ++j)
                pre[ks * 8 + j] = wB[(size_t)((half * 4 + ks) * 32 + j) * D];
        #pragma unroll
        for (int ks = 0; ks < 4; ++ks) {
            short8 b;
            #pragma unroll
            for (int j = 0; j < 8; ++j) b[j] = (short)f2bf(pre[ks * 8 + j]);
            #pragma unroll
            for (int mf = 0; mf < 8; ++mf) {
                short8 a = *(const short8*)(aB + (size_t)(mf * 16) * D + (half * 4 + ks) * 32);
                acc[mf] = __builtin_amdgcn_mfma_f32_16x16x32_bf16(a, b, acc[mf], 0, 0, 0);
            }
        }
    }
    #pragma unroll
    for (int mf = 0; mf < 8; ++mf)
        #pragma unroll
        for (int r = 0; r < 4; ++r)
            Ls[wave][mf * 16 + lqo * 4 + r][lrow] = acc[mf][r];
    __syncthreads();
    #pragma unroll
    for (int m2 = 0; m2 < 2; ++m2)
        #pragma unroll
        for (int r = 0; r < 4; ++r) {
            int row = (wave * 2 + m2) * 16 + lqo * 4 + r;
            float v = Ls[0][row][lrow] + Ls[1][row][lrow] +
                      Ls[2][row][lrow] + Ls[3][row][lrow];
            QKV[(size_t)row * QKVN + n16 + lrow] = v;
        }
}

// ---------------- GU full-K fused + silu epilogue -> Gact bf16 [128][F] ----------------
// 176 blocks; block computes g-cols n0..n0+15 AND u-cols n0..n0+15 (full K),
// 4-wave k-split + two-pass LDS reduce, silu(g)*u in epilogue.
__launch_bounds__(256)
__global__ void gemm_gusilu_kernel(const unsigned short* __restrict__ A,
                                   const float* __restrict__ Wg, const float* __restrict__ Wu,
                                   unsigned short* __restrict__ Gact) {
    __shared__ float Ls[4][128][17];
    const int tid = threadIdx.x, wave = tid >> 6, lane = tid & 63;
    const int lrow = lane & 15, lqo = lane >> 4;
    const int n0 = blockIdx.x * 16;
    const int k0 = wave * 256;
    const unsigned short* aB = A + (size_t)lrow * D + k0 + lqo * 8;
    const float* gB = Wg + (size_t)(k0 + lqo * 8) * F + n0 + lrow;
    const float* uB = Wu + (size_t)(k0 + lqo * 8) * F + n0 + lrow;
    f32x4 aG[8] = {}, aU[8] = {};
    #pragma unroll
    for (int half = 0; half < 2; ++half) {
        float pg[32], pu[32];
        #pragma unroll
        for (int ks = 0; ks < 4; ++ks)
            #pragma unroll
            for (int j = 0; j < 8; ++j) {
                size_t roff = (size_t)((half * 4 + ks) * 32 + j) * F;
                pg[ks * 8 + j] = gB[roff];
                pu[ks * 8 + j] = uB[roff];
            }
        #pragma unroll
        for (int ks = 0; ks < 4; ++ks) {
            short8 bg, bu;
            #pragma unroll
            for (int j = 0; j < 8; ++j) {
                bg[j] = (short)f2bf(pg[ks * 8 + j]);
                bu[j] = (short)f2bf(pu[ks * 8 + j]);
            }
            #pragma unroll
            for (int mf = 0; mf < 8; ++mf) {
                short8 a = *(const short8*)(aB + (size_t)(mf * 16) * D + (half * 4 + ks) * 32);
                aG[mf] = __builtin_amdgcn_mfma_f32_16x16x32_bf16(a, bg, aG[mf], 0, 0, 0);
                aU[mf] = __builtin_amdgcn_mfma_f32_16x16x32_bf16(a, bu, aU[mf], 0, 0, 0);
            }
        }
    }
    // pass 1: reduce G
    #pragma unroll
    for (int mf = 0; mf < 8; ++mf)
        #pragma unroll
        for (int r = 0; r < 4; ++r)
            Ls[wave][mf * 16 + lqo * 4 + r][lrow] = aG[mf][r];
    __syncthreads();
    float gs[8];
    #pragma unroll
    for (int m2 = 0; m2 < 2; ++m2)
        #pragma unroll
        for (int r = 0; r < 4; ++r) {
            int row = (wave * 2 + m2) * 16 + lqo * 4 + r;
            gs[m2 * 4 + r] = Ls[0][row][lrow] + Ls[1][row][lrow] +
                             Ls[2][row][lrow] + Ls[3][row][lrow];
        }
    __syncthreads();
    // pass 2: reduce U, silu, store
    #pragma unroll
    for (int mf = 0; mf < 8; ++mf)
        #pragma unroll
        for (int r = 0; r < 4; ++r)
            Ls[wave][mf * 16 + lqo * 4 + r][lrow] = aU[mf][r];
    __syncthreads();
    #pragma unroll
    for (int m2 = 0; m2 < 2; ++m2)
        #pragma unroll
        for (int r = 0; r < 4; ++r) {
            int row = (wave * 2 + m2) * 16 + lqo * 4 + r;
            float us = Ls[0][row][lrow] + Ls[1][row][lrow] +
                       Ls[2][row][lrow] + Ls[3][row][lrow];
            float g = gs[m2 * 4 + r];
            Gact[(size_t)row * F + n0 + lrow] = f2bf(g / (1.f + __expf(-g)) * us);
        }
}

// ---------------- 64-col staged MFMA GEMM, fp32 [K][N] weights, split-K ----------------
// (round-5 proven) Partial C stored to out + blockIdx.y*chunkStride.
template<int CH>
__launch_bounds__(256)
__global__ void gemm64_kernel(const unsigned short* __restrict__ A, int lda,
                              const float* __restrict__ W, int ldw,
                              float* __restrict__ out, int ldo,
                              size_t chunkStride) {
    constexpr int STAGES = CH / 128;
    constexpr int LSTR = 136;
    __shared__ unsigned short Bst[2][64 * LSTR];
    const int tid = threadIdx.x;
    const int wave = tid >> 6, lane = tid & 63;
    const int n0 = blockIdx.x * 64;
    const int k0 = blockIdx.y * CH;
    const int sc = tid & 63;
    const int so = tid >> 6;
    const float* wCol = W + (size_t)k0 * ldw + n0 + sc;
    unsigned short* wp = &Bst[0][sc * LSTR];
    const int lrow = lane & 15;
    const int lqo = lane >> 4;
    const unsigned short* aB = A + (size_t)lrow * lda + k0 + lqo * 8;
    const unsigned short* bRd = &Bst[0][(wave * 16 + lrow) * LSTR + lqo * 8];
    f32x4 acc[8] = {};
    float pre[32];
    auto ldst = [&](int s) {
        #pragma unroll
        for (int p = 0; p < 4; ++p) {
            const float* src = wCol + (size_t)(s * 128 + (so * 4 + p) * 8) * ldw;
            #pragma unroll
            for (int j = 0; j < 8; ++j) pre[p * 8 + j] = src[(size_t)j * ldw];
        }
    };
    auto wrst = [&](int buf) {
        #pragma unroll
        for (int p = 0; p < 4; ++p) {
            short8 bv;
            #pragma unroll
            for (int j = 0; j < 8; ++j) bv[j] = (short)f2bf(pre[p * 8 + j]);
            *(short8*)(wp + buf * (64 * LSTR) + (so * 4 + p) * 8) = bv;
        }
    };
    ldst(0);
    wrst(0);
    __syncthreads();
    #pragma unroll
    for (int s = 0; s < STAGES; ++s) {
        if (s + 1 < STAGES) ldst(s + 1);
        const unsigned short* rd = bRd + (s & 1) * (64 * LSTR);
        #pragma unroll
        for (int ks = 0; ks < 4; ++ks) {
            short8 b = *(const short8*)(rd + ks * 32);
            #pragma unroll
            for (int mf = 0; mf < 8; ++mf) {
                short8 a = *(const short8*)(aB + (size_t)(mf * 16) * lda + s * 128 + ks * 32);
                acc[mf] = __builtin_amdgcn_mfma_f32_16x16x32_bf16(a, b, acc[mf], 0, 0, 0);
            }
        }
        if (s + 1 < STAGES) {
            __syncthreads();
            wrst((s + 1) & 1);
            __syncthreads();
        }
    }
    const int col = n0 + wave * 16 + lrow;
    float* op = out + blockIdx.y * chunkStride;
    #pragma unroll
    for (int mf = 0; mf < 8; ++mf) {
        int r0 = mf * 16 + lqo * 4;
        #pragma unroll
        for (int r = 0; r < 4; ++r)
            op[(size_t)(r0 + r) * ldo + col] = acc[mf][r];
    }
}

// ---------------- Attention with fused RoPE; QKV is [T][3072] fp32 ----------------
__global__ void attn_rope_kernel(const float* __restrict__ QKV,
                                 const float* __restrict__ cosT, const float* __restrict__ sinT,
                                 unsigned short* __restrict__ AO) {
    int t = blockIdx.x, h = blockIdx.y, lane = threadIdx.x;
    __shared__ float q[DH];
    __shared__ float p[T];
    float qv = QKV[(size_t)t * QKVN + h * DH + lane];
    float qpart = __shfl_xor(qv, 32);
    {
        int i = lane & 31;
        float c = cosT[t * 32 + i], sn = sinT[t * 32 + i];
        q[lane] = (lane < 32) ? (qv * c - qpart * sn) : (qv * c + qpart * sn);
    }
    __syncthreads();
    int j0 = lane, j1 = lane + 64;
    float s0 = -1e30f, s1 = -1e30f;
    if (j0 <= t) {
        const float* kr = QKV + (size_t)j0 * QKVN + D + h * DH;
        const float* cr = cosT + j0 * 32;
        const float* sr = sinT + j0 * 32;
        float s = 0.f;
        #pragma unroll 8
        for (int d = 0; d < 32; ++d) {
            float ka = kr[d], kb = kr[d + 32];
            float c = cr[d], sn = sr[d];
            s += q[d] * (ka * c - kb * sn) + q[d + 32] * (kb * c + ka * sn);
        }
        s0 = s * SCALE;
    }
    if (j1 <= t) {
        const float* kr = QKV + (size_t)j1 * QKVN + D + h * DH;
        const float* cr = cosT + j1 * 32;
        const float* sr = sinT + j1 * 32;
        float s = 0.f;
        #pragma unroll 8
        for (int d = 0; d < 32; ++d) {
            float ka = kr[d], kb = kr[d + 32];
            float c = cr[d], sn = sr[d];
            s += q[d] * (ka * c - kb * sn) + q[d + 32] * (kb * c + ka * sn);
        }
        s1 = s * SCALE;
    }
    float m = fmaxf(s0, s1);
    for (int o = 32; o >= 1; o >>= 1) m = fmaxf(m, __shfl_xor(m, o));
    float e0 = (j0 <= t) ? __expf(s0 - m) : 0.f;
    float e1 = (j1 <= t) ? __expf(s1 - m) : 0.f;
    float sum = e0 + e1;
    for (int o = 32; o >= 1; o >>= 1) sum += __shfl_xor(sum, o);
    float inv = 1.f / sum;
    p[j0] = e0 * inv;
    p[j1] = e1 * inv;
    __syncthreads();
    float acc = 0.f;
    const float* vcol = QKV + 2 * D + h * DH + lane;
    for (int j = 0; j <= t; ++j) acc += p[j] * vcol[(size_t)j * QKVN];
    AO[(size_t)t * D + h * DH + lane] = f2bf(acc);
}

// ---------------- logits: out[v] = emb[v,:] . xl ----------------
__global__ void logits_kernel(const float* __restrict__ emb, const float* __restrict__ xl,
                              float* __restrict__ out) {
    __shared__ float x[D];
    int tid = threadIdx.x;
    ((float4*)x)[tid] = ((const float4*)xl)[tid];
    __syncthreads();
    int row = blockIdx.x * 4 + (tid >> 6);
    int lane = tid & 63;
    const float4* e4 = (const float4*)(emb + (size_t)row * D);
    const float4* x4 = (const float4*)x;
    float s = 0.f;
    #pragma unroll
    for (int k = lane; k < D / 4; k += 64) {
        float4 ev = e4[k], xv = x4[k];
        s += ev.x * xv.x + ev.y * xv.y + ev.z * xv.z + ev.w * xv.w;
    }
    for (int o = 32; o >= 1; o >>= 1) s += __shfl_xor(s, o);
    if (lane == 0) out[row] = s;
}

extern "C" void kernel_launch(void* const* d_in, const int* in_sizes, int n_in,
                              void* d_out, int out_size, void* d_ws, size_t ws_size,
                              hipStream_t stream) {
    const int*   ids = (const int*)d_in[0];
    const float* emb = (const float*)d_in[1];
    const float* Wq  = (const float*)d_in[2];
    const float* Wk  = (const float*)d_in[3];
    const float* Wv  = (const float*)d_in[4];
    const float* Wo  = (const float*)d_in[5];
    const float* Wg  = (const float*)d_in[6];
    const float* Wu  = (const float*)d_in[7];
    const float* Wd  = (const float*)d_in[8];
    const float* attn_norm = (const float*)d_in[9];
    const float* ffn_norm  = (const float*)d_in[10];
    const float* norm_out  = (const float*)d_in[11];
    float* out = (float*)d_out;

    size_t off = 0;
    auto alloc = [&](size_t bytes) {
        void* p = (char*)d_ws + off;
        off += (bytes + 255) & ~(size_t)255;
        return p;
    };
    float*          X     = (float*)alloc((size_t)T * D * 4);
    float*          QKV   = (float*)alloc((size_t)T * QKVN * 4);
    float*          P1    = (float*)alloc((size_t)NP_O * T * D * 4);  // O-proj partials
    float*          P2    = (float*)alloc((size_t)NP_D * T * D * 4);  // Wd partials
    float*          cosT  = (float*)alloc((size_t)T * 32 * 4);
    float*          sinT  = (float*)alloc((size_t)T * 32 * 4);
    float*          xl    = (float*)alloc((size_t)D * 4);
    unsigned short* Hn_bf = (unsigned short*)alloc((size_t)T * D * 2);
    unsigned short* AO_bf = (unsigned short*)alloc((size_t)T * D * 2);
    unsigned short* Gact  = (unsigned short*)alloc((size_t)T * F * 2);
    (void)ws_size;

    embed_rope_kernel<<<T, 256, 0, stream>>>(ids, emb, X, cosT, sinT);

    for (int l = 0; l < L; ++l) {
        const float* wq = Wq + (size_t)l * D * D;
        const float* wk = Wk + (size_t)l * D * D;
        const float* wv = Wv + (size_t)l * D * D;
        const float* wo = Wo + (size_t)l * D * D;
        const float* wg = Wg + (size_t)l * D * F;
        const float* wu = Wu + (size_t)l * D * F;
        const float* wd = Wd + (size_t)l * F * D;

        // X += prev Wd partials; Hn = rmsnorm(X)*attn_norm (bf16)
        if (l == 0)
            rmsnorm_sum_kernel<0, true><<<T, 256, 0, stream>>>(
                X, P2, attn_norm + (size_t)l * D, Hn_bf);
        else
            rmsnorm_sum_kernel<NP_D, true><<<T, 256, 0, stream>>>(
                X, P2, attn_norm + (size_t)l * D, Hn_bf);
        // QKV full-K fused (192 blocks) -> QKV[T][3072] fp32
        gemm_qkv_kernel<<<QKVN / 16, 256, 0, stream>>>(Hn_bf, wq, wk, wv, QKV);
        // attention with inline RoPE -> AO bf16
        attn_rope_kernel<<<dim3(T, H), 64, 0, stream>>>(QKV, cosT, sinT, AO_bf);
        // O-proj split-K (8x128) -> P1 partials
        gemm64_kernel<128><<<dim3(D / 64, NP_O), 256, 0, stream>>>(
            AO_bf, D, wo, D, P1, D, (size_t)T * D);
        // X += P1; Hn = rmsnorm(X)*ffn_norm
        rmsnorm_sum_kernel<NP_O, true><<<T, 256, 0, stream>>>(
            X, P1, ffn_norm + (size_t)l * D, Hn_bf);
        // GU full-K + silu fused (176 blocks) -> Gact bf16
        gemm_gusilu_kernel<<<F / 16, 256, 0, stream>>>(Hn_bf, wg, wu, Gact);
        // Wd split-K (11x256) -> P2 partials (consumed next layer / final)
        gemm64_kernel<256><<<dim3(D / 64, NP_D), 256, 0, stream>>>(
            Gact, F, wd, D, P2, D, (size_t)T * D);
    }

    // final: xl = rmsnorm(X[127] + sum P2[c][127]) * norm_out (fp32)
    rmsnorm_sum_kernel<NP_D, false><<<1, 256, 0, stream>>>(
        X + (size_t)(T - 1) * D, P2 + (size_t)(T - 1) * D, norm_out, xl);
    logits_kernel<<<V / 4, 256, 0, stream>>>(emb, xl, out);
}

// Round 9
// 843.295 us; speedup vs baseline: 7.0136x; 1.0922x over previous
//
#include <hip/hip_runtime.h>
#include <hip/hip_bf16.h>
#include <math.h>

namespace {
constexpr int V = 32000, D = 1024, L = 8, H = 16, T = 128, F = 2816, DH = 64;
constexpr float EPS = 1e-5f;
constexpr float SCALE = 0.125f; // 1/sqrt(DH)
constexpr int QKVN = 3 * D;     // 3072
constexpr int GUN  = 2 * F;     // 5632
constexpr int NP_Q = 4;         // QKV split-K chunks (CH=256)
constexpr int NP_O = 8;         // O-proj chunks (CH=128)
constexpr int NP_G = 4;         // GU chunks (CH=256)
constexpr int NP_D = 11;        // Wd chunks (K=2816 = 11*256)
}

typedef __attribute__((ext_vector_type(8))) short short8;
typedef __attribute__((ext_vector_type(4))) float f32x4;

__device__ __forceinline__ unsigned short f2bf(float x) {
    union { float f; unsigned u; } v; v.f = x;
    unsigned r = v.u + 0x7FFFu + ((v.u >> 16) & 1u);
    return (unsigned short)(r >> 16);
}

// ---------------- Embedding gather + RoPE tables (fused) ----------------
__global__ void embed_rope_kernel(const int* __restrict__ ids, const float* __restrict__ emb,
                                  float* __restrict__ X,
                                  float* __restrict__ cosT, float* __restrict__ sinT) {
    int t = blockIdx.x, tid = threadIdx.x;
    int id = ids[t];
    ((float4*)(X + (size_t)t * D))[tid] = ((const float4*)(emb + (size_t)id * D))[tid];
    if (tid < 32) {
        float inv = powf(10000.0f, -(2.0f * (float)tid) / (float)DH);
        float ang = (float)t * inv;
        cosT[t * 32 + tid] = cosf(ang);
        sinT[t * 32 + tid] = sinf(ang);
    }
}

// ---------------- RMSNorm + unrolled partial-sum residual update ----------------
template<int NP, bool BF16OUT>
__launch_bounds__(256)
__global__ void rmsnorm_sum_kernel(float* __restrict__ X, const float* __restrict__ P,
                                   const float* __restrict__ w, void* __restrict__ Y) {
    int t = blockIdx.x, tid = threadIdx.x;
    float4 xv = ((float4*)(X + (size_t)t * D))[tid];
    #pragma unroll
    for (int c = 0; c < NP; ++c) {
        float4 pv = ((const float4*)(P + ((size_t)c * T + t) * D))[tid];
        xv.x += pv.x; xv.y += pv.y; xv.z += pv.z; xv.w += pv.w;
    }
    if (NP) ((float4*)(X + (size_t)t * D))[tid] = xv;
    float s = xv.x * xv.x + xv.y * xv.y + xv.z * xv.z + xv.w * xv.w;
    for (int o = 32; o >= 1; o >>= 1) s += __shfl_xor(s, o);
    __shared__ float red[4];
    if ((tid & 63) == 0) red[tid >> 6] = s;
    __syncthreads();
    float tot = red[0] + red[1] + red[2] + red[3];
    float r = rsqrtf(tot / (float)D + EPS);
    float4 wv = ((const float4*)w)[tid];
    if (BF16OUT) {
        ushort4 y;
        y.x = f2bf(xv.x * r * wv.x); y.y = f2bf(xv.y * r * wv.y);
        y.z = f2bf(xv.z * r * wv.z); y.w = f2bf(xv.w * r * wv.w);
        ((ushort4*)((unsigned short*)Y + (size_t)t * D))[tid] = y;
    } else {
        float4 y;
        y.x = xv.x * r * wv.x; y.y = xv.y * r * wv.y;
        y.z = xv.z * r * wv.z; y.w = xv.w * r * wv.w;
        ((float4*)((float*)Y + (size_t)t * D))[tid] = y;
    }
}

// ---------------- 64-col staged MFMA GEMM, fp32 [K][N] weights, split-K ----------------
// (round-5 proven) Block: 64 cols, K-chunk CH, W0/W1/W2 via blockIdx.z.
// Partial C stored to out + blockIdx.y*chunkStride, col += zColOff*z.
template<int CH>
__launch_bounds__(256)
__global__ void gemm64_kernel(const unsigned short* __restrict__ A, int lda,
                              const float* __restrict__ W0, const float* __restrict__ W1,
                              const float* __restrict__ W2, int ldw,
                              float* __restrict__ out, int ldo, int zColOff,
                              size_t chunkStride) {
    constexpr int STAGES = CH / 128;
    constexpr int LSTR = 136;
    __shared__ unsigned short Bst[2][64 * LSTR];
    const float* W = blockIdx.z == 0 ? W0 : (blockIdx.z == 1 ? W1 : W2);
    const int tid = threadIdx.x;
    const int wave = tid >> 6, lane = tid & 63;
    const int n0 = blockIdx.x * 64;
    const int k0 = blockIdx.y * CH;
    const int sc = tid & 63;
    const int so = tid >> 6;
    const float* wCol = W + (size_t)k0 * ldw + n0 + sc;
    unsigned short* wp = &Bst[0][sc * LSTR];
    const int lrow = lane & 15;
    const int lqo = lane >> 4;
    const unsigned short* aB = A + (size_t)lrow * lda + k0 + lqo * 8;
    const unsigned short* bRd = &Bst[0][(wave * 16 + lrow) * LSTR + lqo * 8];
    f32x4 acc[8] = {};
    float pre[32];
    auto ldst = [&](int s) {
        #pragma unroll
        for (int p = 0; p < 4; ++p) {
            const float* src = wCol + (size_t)(s * 128 + (so * 4 + p) * 8) * ldw;
            #pragma unroll
            for (int j = 0; j < 8; ++j) pre[p * 8 + j] = src[(size_t)j * ldw];
        }
    };
    auto wrst = [&](int buf) {
        #pragma unroll
        for (int p = 0; p < 4; ++p) {
            short8 bv;
            #pragma unroll
            for (int j = 0; j < 8; ++j) bv[j] = (short)f2bf(pre[p * 8 + j]);
            *(short8*)(wp + buf * (64 * LSTR) + (so * 4 + p) * 8) = bv;
        }
    };
    ldst(0);
    wrst(0);
    __syncthreads();
    #pragma unroll
    for (int s = 0; s < STAGES; ++s) {
        if (s + 1 < STAGES) ldst(s + 1);
        const unsigned short* rd = bRd + (s & 1) * (64 * LSTR);
        #pragma unroll
        for (int ks = 0; ks < 4; ++ks) {
            short8 b = *(const short8*)(rd + ks * 32);
            #pragma unroll
            for (int mf = 0; mf < 8; ++mf) {
                short8 a = *(const short8*)(aB + (size_t)(mf * 16) * lda + s * 128 + ks * 32);
                acc[mf] = __builtin_amdgcn_mfma_f32_16x16x32_bf16(a, b, acc[mf], 0, 0, 0);
            }
        }
        if (s + 1 < STAGES) {
            __syncthreads();
            wrst((s + 1) & 1);
            __syncthreads();
        }
    }
    const int col = zColOff * blockIdx.z + n0 + wave * 16 + lrow;
    float* op = out + blockIdx.y * chunkStride;
    #pragma unroll
    for (int mf = 0; mf < 8; ++mf) {
        int r0 = mf * 16 + lqo * 4;
        #pragma unroll
        for (int r = 0; r < 4; ++r)
            op[(size_t)(r0 + r) * ldo + col] = acc[mf][r];
    }
}

// ---------------- QKV partial reduce + RoPE -> compact Q,K,V [T][D] fp32 ----------------
__launch_bounds__(256)
__global__ void rope_reduce_kernel(const float* __restrict__ P,
                                   const float* __restrict__ cosT, const float* __restrict__ sinT,
                                   float* __restrict__ Qr, float* __restrict__ Kr,
                                   float* __restrict__ Vr) {
    int t = blockIdx.x, tid = threadIdx.x;
    int d0 = tid * 4;
    float4 q = {0.f, 0.f, 0.f, 0.f}, k = q, v = q;
    #pragma unroll
    for (int c = 0; c < NP_Q; ++c) {
        const float* base = P + ((size_t)c * T + t) * QKVN;
        float4 a = ((const float4*)base)[tid];
        float4 b = ((const float4*)(base + D))[tid];
        float4 w = ((const float4*)(base + 2 * D))[tid];
        q.x += a.x; q.y += a.y; q.z += a.z; q.w += a.w;
        k.x += b.x; k.y += b.y; k.z += b.z; k.w += b.w;
        v.x += w.x; v.y += w.y; v.z += w.z; v.w += w.w;
    }
    float4 c4 = *(const float4*)(cosT + t * 32 + (d0 & 31));
    float4 s4 = *(const float4*)(sinT + t * 32 + (d0 & 31));
    float sgn = (d0 & 32) ? 1.f : -1.f;
    float4 qp, kp;
    qp.x = __shfl_xor(q.x, 8); qp.y = __shfl_xor(q.y, 8);
    qp.z = __shfl_xor(q.z, 8); qp.w = __shfl_xor(q.w, 8);
    kp.x = __shfl_xor(k.x, 8); kp.y = __shfl_xor(k.y, 8);
    kp.z = __shfl_xor(k.z, 8); kp.w = __shfl_xor(k.w, 8);
    float4 qo, ko;
    qo.x = q.x * c4.x + sgn * qp.x * s4.x; qo.y = q.y * c4.y + sgn * qp.y * s4.y;
    qo.z = q.z * c4.z + sgn * qp.z * s4.z; qo.w = q.w * c4.w + sgn * qp.w * s4.w;
    ko.x = k.x * c4.x + sgn * kp.x * s4.x; ko.y = k.y * c4.y + sgn * kp.y * s4.y;
    ko.z = k.z * c4.z + sgn * kp.z * s4.z; ko.w = k.w * c4.w + sgn * kp.w * s4.w;
    *(float4*)(Qr + (size_t)t * D + d0) = qo;
    *(float4*)(Kr + (size_t)t * D + d0) = ko;
    *(float4*)(Vr + (size_t)t * D + d0) = v;
}

// ---------------- Causal attention: 4 heads/block, fixed-trip unrolled PV ----------------
__launch_bounds__(256)
__global__ void attn_kernel(const float* __restrict__ Q, const float* __restrict__ Kc,
                            const float* __restrict__ Vc, unsigned short* __restrict__ AO) {
    int t = blockIdx.x;
    int wave = threadIdx.x >> 6, lane = threadIdx.x & 63;
    int h = blockIdx.y * 4 + wave;
    __shared__ float qs[4][64];
    __shared__ float ps[4][128];
    float* q = qs[wave];
    float* p = ps[wave];
    q[lane] = Q[(size_t)t * D + h * DH + lane];
    __syncthreads();
    // scores for j0 = lane, j1 = lane+64 (computed unconditionally, masked after)
    int j0 = lane, j1 = lane + 64;
    const float* kr0 = Kc + (size_t)j0 * D + h * DH;
    const float* kr1 = Kc + (size_t)j1 * D + h * DH;
    float s0 = 0.f, s1 = 0.f;
    #pragma unroll
    for (int d = 0; d < DH; ++d) {
        float qd = q[d];
        s0 = fmaf(qd, kr0[d], s0);
        s1 = fmaf(qd, kr1[d], s1);
    }
    s0 = (j0 <= t) ? s0 * SCALE : -1e30f;
    s1 = (j1 <= t) ? s1 * SCALE : -1e30f;
    float m = fmaxf(s0, s1);
    for (int o = 32; o >= 1; o >>= 1) m = fmaxf(m, __shfl_xor(m, o));
    float e0 = (j0 <= t) ? __expf(s0 - m) : 0.f;
    float e1 = (j1 <= t) ? __expf(s1 - m) : 0.f;
    float sum = e0 + e1;
    for (int o = 32; o >= 1; o >>= 1) sum += __shfl_xor(sum, o);
    float inv = 1.f / sum;
    p[j0] = e0 * inv;   // p[j] = 0 for j > t  -> fixed-trip PV below is exact
    p[j1] = e1 * inv;
    __syncthreads();
    // PV: fixed 128 trips, fully unrolled, 4 independent accumulator chains
    const float* vcol = Vc + h * DH + lane;
    float a0 = 0.f, a1 = 0.f, a2 = 0.f, a3 = 0.f;
    #pragma unroll
    for (int j = 0; j < T; j += 4) {
        a0 = fmaf(p[j],     vcol[(size_t)(j)     * D], a0);
        a1 = fmaf(p[j + 1], vcol[(size_t)(j + 1) * D], a1);
        a2 = fmaf(p[j + 2], vcol[(size_t)(j + 2) * D], a2);
        a3 = fmaf(p[j + 3], vcol[(size_t)(j + 3) * D], a3);
    }
    AO[(size_t)t * D + h * DH + lane] = f2bf((a0 + a1) + (a2 + a3));
}

// ---------------- GU partial reduce + silu(g)*u -> Gact bf16 [T][F] ----------------
__launch_bounds__(256)
__global__ void silu_reduce_kernel(const float* __restrict__ P,
                                   unsigned short* __restrict__ Gact) {
    int t = blockIdx.y;
    int f = blockIdx.x * 256 + threadIdx.x;
    float g = 0.f, u = 0.f;
    #pragma unroll
    for (int c = 0; c < NP_G; ++c) {
        const float* base = P + ((size_t)c * T + t) * GUN;
        g += base[f];
        u += base[F + f];
    }
    Gact[(size_t)t * F + f] = f2bf(g / (1.f + __expf(-g)) * u);
}

// ---------------- logits: out[v] = emb[v,:] . xl ----------------
__global__ void logits_kernel(const float* __restrict__ emb, const float* __restrict__ xl,
                              float* __restrict__ out) {
    __shared__ float x[D];
    int tid = threadIdx.x;
    ((float4*)x)[tid] = ((const float4*)xl)[tid];
    __syncthreads();
    int row = blockIdx.x * 4 + (tid >> 6);
    int lane = tid & 63;
    const float4* e4 = (const float4*)(emb + (size_t)row * D);
    const float4* x4 = (const float4*)x;
    float s = 0.f;
    #pragma unroll
    for (int k = lane; k < D / 4; k += 64) {
        float4 ev = e4[k], xv = x4[k];
        s += ev.x * xv.x + ev.y * xv.y + ev.z * xv.z + ev.w * xv.w;
    }
    for (int o = 32; o >= 1; o >>= 1) s += __shfl_xor(s, o);
    if (lane == 0) out[row] = s;
}

extern "C" void kernel_launch(void* const* d_in, const int* in_sizes, int n_in,
                              void* d_out, int out_size, void* d_ws, size_t ws_size,
                              hipStream_t stream) {
    const int*   ids = (const int*)d_in[0];
    const float* emb = (const float*)d_in[1];
    const float* Wq  = (const float*)d_in[2];
    const float* Wk  = (const float*)d_in[3];
    const float* Wv  = (const float*)d_in[4];
    const float* Wo  = (const float*)d_in[5];
    const float* Wg  = (const float*)d_in[6];
    const float* Wu  = (const float*)d_in[7];
    const float* Wd  = (const float*)d_in[8];
    const float* attn_norm = (const float*)d_in[9];
    const float* ffn_norm  = (const float*)d_in[10];
    const float* norm_out  = (const float*)d_in[11];
    float* out = (float*)d_out;

    size_t off = 0;
    auto alloc = [&](size_t bytes) {
        void* p = (char*)d_ws + off;
        off += (bytes + 255) & ~(size_t)255;
        return p;
    };
    float*          X     = (float*)alloc((size_t)T * D * 4);
    float*          P0    = (float*)alloc((size_t)NP_Q * T * QKVN * 4);  // QKV partials
    float*          P1    = (float*)alloc((size_t)NP_O * T * D * 4);     // O-proj partials
    float*          P2    = (float*)alloc((size_t)NP_D * T * D * 4);     // Wd partials
    float*          P3    = (float*)alloc((size_t)NP_G * T * GUN * 4);   // GU partials
    float*          Qr    = (float*)alloc((size_t)T * D * 4);
    float*          Kr    = (float*)alloc((size_t)T * D * 4);
    float*          Vr    = (float*)alloc((size_t)T * D * 4);
    float*          cosT  = (float*)alloc((size_t)T * 32 * 4);
    float*          sinT  = (float*)alloc((size_t)T * 32 * 4);
    float*          xl    = (float*)alloc((size_t)D * 4);
    unsigned short* Hn_bf = (unsigned short*)alloc((size_t)T * D * 2);
    unsigned short* AO_bf = (unsigned short*)alloc((size_t)T * D * 2);
    unsigned short* Gact  = (unsigned short*)alloc((size_t)T * F * 2);
    (void)ws_size;

    embed_rope_kernel<<<T, 256, 0, stream>>>(ids, emb, X, cosT, sinT);

    for (int l = 0; l < L; ++l) {
        const float* wq = Wq + (size_t)l * D * D;
        const float* wk = Wk + (size_t)l * D * D;
        const float* wv = Wv + (size_t)l * D * D;
        const float* wo = Wo + (size_t)l * D * D;
        const float* wg = Wg + (size_t)l * D * F;
        const float* wu = Wu + (size_t)l * D * F;
        const float* wd = Wd + (size_t)l * F * D;

        // X += prev Wd partials; Hn = rmsnorm(X)*attn_norm (bf16)
        if (l == 0)
            rmsnorm_sum_kernel<0, true><<<T, 256, 0, stream>>>(
                X, P2, attn_norm + (size_t)l * D, Hn_bf);
        else
            rmsnorm_sum_kernel<NP_D, true><<<T, 256, 0, stream>>>(
                X, P2, attn_norm + (size_t)l * D, Hn_bf);
        // QKV partials: 64-col, K=1024 split 4x256, z in {q,k,v} -> 192 blocks
        gemm64_kernel<256><<<dim3(D / 64, NP_Q, 3), 256, 0, stream>>>(
            Hn_bf, D, wq, wk, wv, D, P0, QKVN, D, (size_t)T * QKVN);
        rope_reduce_kernel<<<T, 256, 0, stream>>>(P0, cosT, sinT, Qr, Kr, Vr);
        // attention: 4 heads/block, fixed-trip unrolled PV -> 512 blocks
        attn_kernel<<<dim3(T, H / 4), 256, 0, stream>>>(Qr, Kr, Vr, AO_bf);
        // O-proj partials: K=1024 split 8x128 -> 128 blocks
        gemm64_kernel<128><<<dim3(D / 64, NP_O, 1), 256, 0, stream>>>(
            AO_bf, D, wo, wo, wo, D, P1, D, 0, (size_t)T * D);
        rmsnorm_sum_kernel<NP_O, true><<<T, 256, 0, stream>>>(
            X, P1, ffn_norm + (size_t)l * D, Hn_bf);
        // GU partials: K=1024 split 4x256, z in {g,u} -> 352 blocks
        gemm64_kernel<256><<<dim3(F / 64, NP_G, 2), 256, 0, stream>>>(
            Hn_bf, D, wg, wu, wu, F, P3, GUN, F, (size_t)T * GUN);
        silu_reduce_kernel<<<dim3(F / 256, T), 256, 0, stream>>>(P3, Gact);
        // Wd partials: K=2816 split 11x256 -> 176 blocks
        gemm64_kernel<256><<<dim3(D / 64, NP_D, 1), 256, 0, stream>>>(
            Gact, F, wd, wd, wd, D, P2, D, 0, (size_t)T * D);
    }

    // final: xl = rmsnorm(X[127] + sum P2[c][127]) * norm_out (fp32)
    rmsnorm_sum_kernel<NP_D, false><<<1, 256, 0, stream>>>(
        X + (size_t)(T - 1) * D, P2 + (size_t)(T - 1) * D, norm_out, xl);
    logits_kernel<<<V / 4, 256, 0, stream>>>(emb, xl, out);
}